// Round 1
// baseline (508.058 us; speedup 1.0000x reference)
//
#include <hip/hip_runtime.h>
#include <math.h>

#define NN 256
#define CZ 128
#define NH 4
#define CH 32
#define HC 128
#define NPIX (NN*NN)
#define SCALE 0.17677669529663687f  // 1/sqrt(32)

// ---------------------------------------------------------------------------
// Kernel 1: fused LayerNorm + projections (q,k,v,g,bias)
// block = 256 threads, handles 32 pixels (one row-chunk, same i for all)
// Layouts written:
//   q_t   [i][h][c][j]   (transposed so attention lane=j reads coalesced)
//   k_ws  [i][h][j][c]
//   v_ws  [i][h][j][c]
//   g_ws  [pixel][h*C+c] (pixel-major, sigmoid already applied)
//   bias_t[h][k][j]      (bias[b,j,k,h] stored at h*NPIX + k*256 + j)
// ---------------------------------------------------------------------------
__global__ __launch_bounds__(256) void ln_proj_kernel(
    const float* __restrict__ z, const float* __restrict__ ls, const float* __restrict__ lb,
    const float* __restrict__ Wq, const float* __restrict__ Wk, const float* __restrict__ Wv,
    const float* __restrict__ Wb, const float* __restrict__ Wg,
    float* __restrict__ q_t, float* __restrict__ k_ws, float* __restrict__ v_ws,
    float* __restrict__ g_ws, float* __restrict__ bias_t)
{
    __shared__ float zsh[32][128];
    __shared__ float rsum[256], rsq[256];
    __shared__ float pmu[32], prs[32];

    const int t  = threadIdx.x;
    const int p0 = blockIdx.x * 32;     // base pixel; 32 | 256 so whole tile shares i
    const int i  = p0 >> 8;
    const int j0 = p0 & 255;

    // ---- load 32x128 tile (float4, coalesced) ----
    const float4* z4 = (const float4*)(z + (size_t)p0 * CZ);
    #pragma unroll
    for (int r = 0; r < 4; ++r) {
        int idx4 = t + 256 * r;
        int p = idx4 >> 5, pos = idx4 & 31;
        float4 v = z4[idx4];
        *(float4*)&zsh[p][pos * 4] = v;
    }
    __syncthreads();

    // ---- mean/var: 8 threads per pixel ----
    {
        int p = t >> 3, sg = t & 7;
        float s = 0.f, q = 0.f;
        #pragma unroll
        for (int u = 0; u < 16; ++u) { float x = zsh[p][sg * 16 + u]; s += x; q += x * x; }
        rsum[t] = s; rsq[t] = q;
    }
    __syncthreads();
    if (t < 32) {
        float s = 0.f, q = 0.f;
        #pragma unroll
        for (int g = 0; g < 8; ++g) { s += rsum[t * 8 + g]; q += rsq[t * 8 + g]; }
        float mu  = s * (1.0f / 128.0f);
        float var = q * (1.0f / 128.0f) - mu * mu;
        float a   = var + 1e-5f;
        float r   = rsqrtf(a);
        r = r * (1.5f - 0.5f * a * r * r);   // one Newton step for accuracy
        pmu[t] = mu; prs[t] = r;
    }
    __syncthreads();

    // ---- normalize in LDS ----
    #pragma unroll
    for (int r4 = 0; r4 < 4; ++r4) {
        int idx4 = t + 256 * r4;
        int p = idx4 >> 5, pos = idx4 & 31;
        float4 v  = *(float4*)&zsh[p][pos * 4];
        float4 s4 = ((const float4*)ls)[pos];
        float4 b4 = ((const float4*)lb)[pos];
        float mu = pmu[p], rs = prs[p];
        v.x = (v.x - mu) * rs * s4.x + b4.x;
        v.y = (v.y - mu) * rs * s4.y + b4.y;
        v.z = (v.z - mu) * rs * s4.z + b4.z;
        v.w = (v.w - mu) * rs * s4.w + b4.w;
        *(float4*)&zsh[p][pos * 4] = v;
    }
    __syncthreads();

    // ---- GEMM: thread handles 2 cols x 32 pixels ----
    const int half = t >> 7;           // 0: q/v   1: k/g
    const int c    = t & 127;
    const float* __restrict__ W0 = half ? Wk : Wq;
    const float* __restrict__ W1 = half ? Wg : Wv;

    float acc0[32], acc1[32];
    #pragma unroll
    for (int p = 0; p < 32; ++p) { acc0[p] = 0.f; acc1[p] = 0.f; }

    for (int d = 0; d < 128; ++d) {
        float w0 = W0[d * 128 + c];
        float w1 = W1[d * 128 + c];
        #pragma unroll
        for (int p = 0; p < 32; ++p) {
            float zv = zsh[p][d];          // wave-uniform LDS broadcast
            acc0[p] = fmaf(zv, w0, acc0[p]);
            acc1[p] = fmaf(zv, w1, acc1[p]);
        }
    }

    // ---- epilogue ----
    const int h = c >> 5, cc = c & 31;
    if (half == 0) {
        // q transposed: each thread writes a contiguous 128B run over j
        float* qp = q_t + ((size_t)(i * NH + h) * CH + cc) * NN + j0;
        #pragma unroll
        for (int p = 0; p < 32; ++p) qp[p] = acc0[p];
        float* vp = v_ws + ((size_t)(i * NH + h) * NN + j0) * CH + cc;
        #pragma unroll
        for (int p = 0; p < 32; ++p) vp[p * CH] = acc1[p];
    } else {
        float* kp = k_ws + ((size_t)(i * NH + h) * NN + j0) * CH + cc;
        #pragma unroll
        for (int p = 0; p < 32; ++p) kp[p * CH] = acc0[p];
        float* gp = g_ws + (size_t)p0 * HC + c;
        #pragma unroll
        for (int p = 0; p < 32; ++p) gp[p * HC] = 1.0f / (1.0f + __expf(-acc1[p]));
    }

    // ---- bias = zn @ Wb  (threads 0..127: one (pixel,h) dot each) ----
    if (t < 128) {
        int p = t >> 2, hh = t & 3;
        float b = 0.f;
        for (int d = 0; d < 128; ++d) b = fmaf(zsh[p][d], Wb[d * 4 + hh], b);
        // pixel (row=i, col=j0+p) -> bias_t[h][col][row]
        bias_t[(size_t)hh * NPIX + (size_t)(j0 + p) * NN + i] = b;
    }
}

// ---------------------------------------------------------------------------
// Kernel 2: attention per (i,h). 256 threads = one thread per query j.
// Flash-style online softmax over k; K/V staged in LDS (broadcast reads).
// Writes go = g * softmax(qk+bias) @ v  in pixel-major layout.
// ---------------------------------------------------------------------------
__global__ __launch_bounds__(256, 2) void attn_kernel(
    const float* __restrict__ q_t, const float* __restrict__ k_ws, const float* __restrict__ v_ws,
    const float* __restrict__ g_ws, const float* __restrict__ bias_t, float* __restrict__ go_ws)
{
    __shared__ float Ksh[NN * CH];   // 32 KB
    __shared__ float Vsh[NN * CH];   // 32 KB

    const int t = threadIdx.x;
    const int h = blockIdx.x & 3;
    const int i = blockIdx.x >> 2;

    const float* kb = k_ws + (size_t)(i * NH + h) * NN * CH;
    const float* vb = v_ws + (size_t)(i * NH + h) * NN * CH;
    #pragma unroll
    for (int r = 0; r < 8; ++r) {
        int idx4 = t + 256 * r;
        ((float4*)Ksh)[idx4] = ((const float4*)kb)[idx4];
        ((float4*)Vsh)[idx4] = ((const float4*)vb)[idx4];
    }
    __syncthreads();

    const int j = t;
    const float* qrow = q_t + (size_t)(i * NH + h) * CH * NN;
    const float* brow = bias_t + (size_t)h * NPIX;

    float qreg[32];
    #pragma unroll
    for (int cc = 0; cc < 32; ++cc) qreg[cc] = qrow[cc * NN + j];   // coalesced

    float o[32];
    #pragma unroll
    for (int cc = 0; cc < 32; ++cc) o[cc] = 0.f;
    float m = -1e30f, l = 0.f;

    for (int t0 = 0; t0 < NN; t0 += 32) {
        float s[32];
        #pragma unroll
        for (int kk = 0; kk < 32; ++kk) s[kk] = 0.f;

        #pragma unroll
        for (int kk = 0; kk < 32; ++kk) {
            const float4* kr = (const float4*)(Ksh + (t0 + kk) * CH);
            #pragma unroll
            for (int c4 = 0; c4 < 8; ++c4) {
                float4 kv = kr[c4];   // wave-uniform ds_read_b128 broadcast
                s[kk] = fmaf(qreg[c4 * 4 + 0], kv.x, s[kk]);
                s[kk] = fmaf(qreg[c4 * 4 + 1], kv.y, s[kk]);
                s[kk] = fmaf(qreg[c4 * 4 + 2], kv.z, s[kk]);
                s[kk] = fmaf(qreg[c4 * 4 + 3], kv.w, s[kk]);
            }
        }
        #pragma unroll
        for (int kk = 0; kk < 32; ++kk) {
            float bv = brow[(t0 + kk) * NN + j];   // coalesced
            s[kk] = fmaf(s[kk], SCALE, bv);
        }

        float mt = s[0];
        #pragma unroll
        for (int kk = 1; kk < 32; ++kk) mt = fmaxf(mt, s[kk]);
        float mnew  = fmaxf(m, mt);
        float alpha = __expf(m - mnew);
        float sl = 0.f;
        #pragma unroll
        for (int kk = 0; kk < 32; ++kk) { s[kk] = __expf(s[kk] - mnew); sl += s[kk]; }
        l = l * alpha + sl;
        m = mnew;
        #pragma unroll
        for (int cc = 0; cc < 32; ++cc) o[cc] *= alpha;

        #pragma unroll
        for (int kk = 0; kk < 32; ++kk) {
            float p = s[kk];
            const float4* vr = (const float4*)(Vsh + (t0 + kk) * CH);
            #pragma unroll
            for (int c4 = 0; c4 < 8; ++c4) {
                float4 vv = vr[c4];   // broadcast
                o[c4 * 4 + 0] = fmaf(p, vv.x, o[c4 * 4 + 0]);
                o[c4 * 4 + 1] = fmaf(p, vv.y, o[c4 * 4 + 1]);
                o[c4 * 4 + 2] = fmaf(p, vv.z, o[c4 * 4 + 2]);
                o[c4 * 4 + 3] = fmaf(p, vv.w, o[c4 * 4 + 3]);
            }
        }
    }

    const float invl = 1.0f / l;
    const size_t pix = (size_t)i * NN + j;
    const float4* gp  = (const float4*)(g_ws + pix * HC + h * CH);
    float4*       gop = (float4*)(go_ws + pix * HC + h * CH);
    #pragma unroll
    for (int c4 = 0; c4 < 8; ++c4) {
        float4 g4 = gp[c4];
        float4 r;
        r.x = g4.x * o[c4 * 4 + 0] * invl;
        r.y = g4.y * o[c4 * 4 + 1] * invl;
        r.z = g4.z * o[c4 * 4 + 2] * invl;
        r.w = g4.w * o[c4 * 4 + 3] * invl;
        gop[c4] = r;
    }
}

// ---------------------------------------------------------------------------
// Kernel 3: out = go @ Wo   ([65536,128] @ [128,128])
// ---------------------------------------------------------------------------
__global__ __launch_bounds__(256) void outproj_kernel(
    const float* __restrict__ go_ws, const float* __restrict__ Wo, float* __restrict__ out)
{
    __shared__ float gsh[32][128];
    const int t  = threadIdx.x;
    const int p0 = blockIdx.x * 32;

    const float4* g4 = (const float4*)(go_ws + (size_t)p0 * HC);
    #pragma unroll
    for (int r = 0; r < 4; ++r) {
        int idx4 = t + 256 * r;
        int p = idx4 >> 5, pos = idx4 & 31;
        *(float4*)&gsh[p][pos * 4] = g4[idx4];
    }
    __syncthreads();

    const int c = t & 127, grp = t >> 7;
    float acc[16];
    #pragma unroll
    for (int u = 0; u < 16; ++u) acc[u] = 0.f;

    for (int d = 0; d < 128; ++d) {
        float w = Wo[d * 128 + c];
        #pragma unroll
        for (int u = 0; u < 16; ++u)
            acc[u] = fmaf(gsh[grp * 16 + u][d], w, acc[u]);
    }

    float* op = out + (size_t)(p0 + grp * 16) * HC + c;
    #pragma unroll
    for (int u = 0; u < 16; ++u) op[u * HC] = acc[u];
}

// ---------------------------------------------------------------------------
extern "C" void kernel_launch(void* const* d_in, const int* in_sizes, int n_in,
                              void* d_out, int out_size, void* d_ws, size_t ws_size,
                              hipStream_t stream)
{
    const float* z  = (const float*)d_in[0];
    const float* ls = (const float*)d_in[1];
    const float* lb = (const float*)d_in[2];
    const float* Wq = (const float*)d_in[3];
    const float* Wk = (const float*)d_in[4];
    const float* Wv = (const float*)d_in[5];
    const float* Wb = (const float*)d_in[6];
    const float* Wg = (const float*)d_in[7];
    const float* Wo = (const float*)d_in[8];

    float* ws = (float*)d_ws;
    const size_t BIG = (size_t)NPIX * HC;   // 8.39M floats each
    float* q_t    = ws;
    float* k_ws   = ws + BIG;
    float* v_ws   = ws + 2 * BIG;
    float* g_ws   = ws + 3 * BIG;
    float* go_ws  = ws + 4 * BIG;
    float* bias_t = ws + 5 * BIG;           // +262144 floats -> ~169 MB total

    ln_proj_kernel<<<NPIX / 32, 256, 0, stream>>>(z, ls, lb, Wq, Wk, Wv, Wb, Wg,
                                                  q_t, k_ws, v_ws, g_ws, bias_t);
    attn_kernel<<<NN * NH, 256, 0, stream>>>(q_t, k_ws, v_ws, g_ws, bias_t, go_ws);
    outproj_kernel<<<NPIX / 32, 256, 0, stream>>>(go_ws, Wo, (float*)d_out);
}

// Round 2
// 433.176 us; speedup vs baseline: 1.1729x; 1.1729x over previous
//
#include <hip/hip_runtime.h>
#include <math.h>

#define NN 256
#define CZ 128
#define NH 4
#define CH 32
#define HC 128
#define NPIX (NN*NN)
#define SCALE 0.17677669529663687f  // 1/sqrt(32)

// ---------------------------------------------------------------------------
// Kernel 1: fused LayerNorm + projections (q,k,v,g,bias)
// block = 256 threads, 32 pixels (same i). Thread tile: 16 pixels x 4 cols.
// zn read from LDS via ds_read_b128 broadcast (4 d's per read).
// Layouts written:
//   q_t   [i][h][c][j]
//   k_ws  [i][h][j][c]
//   v_ws  [i][h][j][c]
//   g_ws  [pixel][h*C+c]  (sigmoid applied)
//   bias_t[h][zcol][zrow]
// ---------------------------------------------------------------------------
__global__ __launch_bounds__(256) void ln_proj_kernel(
    const float* __restrict__ z, const float* __restrict__ ls, const float* __restrict__ lb,
    const float* __restrict__ Wq, const float* __restrict__ Wk, const float* __restrict__ Wv,
    const float* __restrict__ Wb, const float* __restrict__ Wg,
    float* __restrict__ q_t, float* __restrict__ k_ws, float* __restrict__ v_ws,
    float* __restrict__ g_ws, float* __restrict__ bias_t)
{
    __shared__ float zsh[32][132];        // +4 pad: row stride 132 breaks bank alignment
    __shared__ float rsum[256], rsq[256];
    __shared__ float pmu[32], prs[32];

    const int t  = threadIdx.x;
    const int p0 = blockIdx.x * 32;
    const int i  = p0 >> 8;
    const int j0 = p0 & 255;

    // ---- load 32x128 tile (float4, coalesced) ----
    const float4* z4 = (const float4*)(z + (size_t)p0 * CZ);
    #pragma unroll
    for (int r = 0; r < 4; ++r) {
        int idx4 = t + 256 * r;
        int p = idx4 >> 5, pos = idx4 & 31;
        *(float4*)&zsh[p][pos * 4] = z4[idx4];
    }
    __syncthreads();

    // ---- mean/var: 8 threads per pixel ----
    {
        int p = t >> 3, sg = t & 7;
        float s = 0.f, q = 0.f;
        #pragma unroll
        for (int u = 0; u < 16; ++u) { float x = zsh[p][sg * 16 + u]; s += x; q += x * x; }
        rsum[t] = s; rsq[t] = q;
    }
    __syncthreads();
    if (t < 32) {
        float s = 0.f, q = 0.f;
        #pragma unroll
        for (int g = 0; g < 8; ++g) { s += rsum[t * 8 + g]; q += rsq[t * 8 + g]; }
        float mu  = s * (1.0f / 128.0f);
        float var = q * (1.0f / 128.0f) - mu * mu;
        float a   = var + 1e-5f;
        float r   = rsqrtf(a);
        r = r * (1.5f - 0.5f * a * r * r);   // one Newton step
        pmu[t] = mu; prs[t] = r;
    }
    __syncthreads();

    // ---- normalize in LDS ----
    #pragma unroll
    for (int r4 = 0; r4 < 4; ++r4) {
        int idx4 = t + 256 * r4;
        int p = idx4 >> 5, pos = idx4 & 31;
        float4 v  = *(float4*)&zsh[p][pos * 4];
        float4 s4 = ((const float4*)ls)[pos];
        float4 b4 = ((const float4*)lb)[pos];
        float mu = pmu[p], rs = prs[p];
        v.x = (v.x - mu) * rs * s4.x + b4.x;
        v.y = (v.y - mu) * rs * s4.y + b4.y;
        v.z = (v.z - mu) * rs * s4.z + b4.z;
        v.w = (v.w - mu) * rs * s4.w + b4.w;
        *(float4*)&zsh[p][pos * 4] = v;
    }
    __syncthreads();

    // ---- GEMM: thread tile = 16 pixels x 4 consecutive cols ----
    const int pg  = t >> 7;           // pixel group (0/1)
    const int cg  = t & 127;          // col group: 4 cols each, 512 cols total
    const int c0  = cg * 4;
    const int mtx = c0 >> 7;          // 0:q 1:k 2:v 3:g
    const int cw  = c0 & 127;         // col within matrix
    const int h   = cw >> 5, cc = cw & 31;
    const int pp0 = pg * 16;
    const float* __restrict__ Wm = (mtx == 0) ? Wq : (mtx == 1) ? Wk : (mtx == 2) ? Wv : Wg;

    float4 acc[16];
    #pragma unroll
    for (int p = 0; p < 16; ++p) acc[p] = make_float4(0.f, 0.f, 0.f, 0.f);

    for (int d0 = 0; d0 < 128; d0 += 4) {
        float4 w0 = *(const float4*)(Wm + (size_t)(d0 + 0) * 128 + cw);
        float4 w1 = *(const float4*)(Wm + (size_t)(d0 + 1) * 128 + cw);
        float4 w2 = *(const float4*)(Wm + (size_t)(d0 + 2) * 128 + cw);
        float4 w3 = *(const float4*)(Wm + (size_t)(d0 + 3) * 128 + cw);
        #pragma unroll
        for (int p = 0; p < 16; ++p) {
            float4 zv = *(const float4*)&zsh[pp0 + p][d0];   // ds_read_b128 broadcast
            acc[p].x = fmaf(zv.x, w0.x, acc[p].x);
            acc[p].x = fmaf(zv.y, w1.x, acc[p].x);
            acc[p].x = fmaf(zv.z, w2.x, acc[p].x);
            acc[p].x = fmaf(zv.w, w3.x, acc[p].x);
            acc[p].y = fmaf(zv.x, w0.y, acc[p].y);
            acc[p].y = fmaf(zv.y, w1.y, acc[p].y);
            acc[p].y = fmaf(zv.z, w2.y, acc[p].y);
            acc[p].y = fmaf(zv.w, w3.y, acc[p].y);
            acc[p].z = fmaf(zv.x, w0.z, acc[p].z);
            acc[p].z = fmaf(zv.y, w1.z, acc[p].z);
            acc[p].z = fmaf(zv.z, w2.z, acc[p].z);
            acc[p].z = fmaf(zv.w, w3.z, acc[p].z);
            acc[p].w = fmaf(zv.x, w0.w, acc[p].w);
            acc[p].w = fmaf(zv.y, w1.w, acc[p].w);
            acc[p].w = fmaf(zv.z, w2.w, acc[p].w);
            acc[p].w = fmaf(zv.w, w3.w, acc[p].w);
        }
    }

    // ---- epilogue (per matrix) ----
    if (mtx == 0) {
        // q_t[i][h][c][j]: 4 runs of 16 consecutive j
        #pragma unroll
        for (int cj = 0; cj < 4; ++cj) {
            float* qp = q_t + ((size_t)(i * NH + h) * CH + cc + cj) * NN + j0 + pp0;
            #pragma unroll
            for (int p = 0; p < 16; ++p)
                qp[p] = (cj == 0) ? acc[p].x : (cj == 1) ? acc[p].y : (cj == 2) ? acc[p].z : acc[p].w;
        }
    } else if (mtx == 1) {
        float* kp = k_ws + ((size_t)(i * NH + h) * NN + j0 + pp0) * CH + cc;
        #pragma unroll
        for (int p = 0; p < 16; ++p) *(float4*)(kp + (size_t)p * CH) = acc[p];
    } else if (mtx == 2) {
        float* vp = v_ws + ((size_t)(i * NH + h) * NN + j0 + pp0) * CH + cc;
        #pragma unroll
        for (int p = 0; p < 16; ++p) *(float4*)(vp + (size_t)p * CH) = acc[p];
    } else {
        float* gp = g_ws + (size_t)(p0 + pp0) * HC + cw;
        #pragma unroll
        for (int p = 0; p < 16; ++p) {
            float4 r;
            r.x = 1.0f / (1.0f + __expf(-acc[p].x));
            r.y = 1.0f / (1.0f + __expf(-acc[p].y));
            r.z = 1.0f / (1.0f + __expf(-acc[p].z));
            r.w = 1.0f / (1.0f + __expf(-acc[p].w));
            *(float4*)(gp + (size_t)p * HC) = r;
        }
    }

    // ---- bias = zn @ Wb  (threads 0..127: one (pixel,h) dot each) ----
    if (t < 128) {
        int p = t >> 2, hh = t & 3;
        float b = 0.f;
        for (int d = 0; d < 128; ++d) b = fmaf(zsh[p][d], Wb[d * 4 + hh], b);
        bias_t[(size_t)hh * NPIX + (size_t)(j0 + p) * NN + i] = b;   // [h][zcol][zrow]
    }
}

// ---------------------------------------------------------------------------
// Kernel 2: attention per (i,h). 128 threads, 2 queries per thread (j, j+128).
// Flash-style online softmax, 16-key chunks; K/V staged fp32 in LDS.
// Each b128 broadcast of K/V now feeds 8 fmas (2 queries) instead of 4.
// ---------------------------------------------------------------------------
__global__ __launch_bounds__(128) void attn_kernel(
    const float* __restrict__ q_t, const float* __restrict__ k_ws, const float* __restrict__ v_ws,
    const float* __restrict__ g_ws, const float* __restrict__ bias_t, float* __restrict__ go_ws)
{
    __shared__ float Ksh[NN * CH];   // 32 KB
    __shared__ float Vsh[NN * CH];   // 32 KB

    const int t = threadIdx.x;
    const int h = blockIdx.x & 3;
    const int i = blockIdx.x >> 2;

    const float4* kb4 = (const float4*)(k_ws + (size_t)(i * NH + h) * NN * CH);
    const float4* vb4 = (const float4*)(v_ws + (size_t)(i * NH + h) * NN * CH);
    #pragma unroll
    for (int r = 0; r < 16; ++r) {
        int idx = t + 128 * r;
        ((float4*)Ksh)[idx] = kb4[idx];
        ((float4*)Vsh)[idx] = vb4[idx];
    }
    __syncthreads();

    const int j0 = t, j1 = t + 128;
    const float* qrow = q_t + (size_t)(i * NH + h) * CH * NN;
    const float* brow = bias_t + (size_t)h * NPIX;

    float q0[32], q1[32];
    #pragma unroll
    for (int cc = 0; cc < 32; ++cc) { q0[cc] = qrow[cc * NN + j0]; q1[cc] = qrow[cc * NN + j1]; }

    float o0[32], o1[32];
    #pragma unroll
    for (int cc = 0; cc < 32; ++cc) { o0[cc] = 0.f; o1[cc] = 0.f; }
    float m0 = -1e30f, l0 = 0.f, m1 = -1e30f, l1 = 0.f;

    for (int t0 = 0; t0 < NN; t0 += 16) {
        float s0[16], s1[16];
        #pragma unroll
        for (int kk = 0; kk < 16; ++kk) { s0[kk] = 0.f; s1[kk] = 0.f; }

        #pragma unroll
        for (int kk = 0; kk < 16; ++kk) {
            const float4* kr = (const float4*)(Ksh + (t0 + kk) * CH);
            #pragma unroll
            for (int c4 = 0; c4 < 8; ++c4) {
                float4 kv = kr[c4];   // broadcast ds_read_b128, shared by both queries
                s0[kk] = fmaf(q0[c4 * 4 + 0], kv.x, s0[kk]);
                s0[kk] = fmaf(q0[c4 * 4 + 1], kv.y, s0[kk]);
                s0[kk] = fmaf(q0[c4 * 4 + 2], kv.z, s0[kk]);
                s0[kk] = fmaf(q0[c4 * 4 + 3], kv.w, s0[kk]);
                s1[kk] = fmaf(q1[c4 * 4 + 0], kv.x, s1[kk]);
                s1[kk] = fmaf(q1[c4 * 4 + 1], kv.y, s1[kk]);
                s1[kk] = fmaf(q1[c4 * 4 + 2], kv.z, s1[kk]);
                s1[kk] = fmaf(q1[c4 * 4 + 3], kv.w, s1[kk]);
            }
        }
        #pragma unroll
        for (int kk = 0; kk < 16; ++kk) {
            float bv0 = brow[(t0 + kk) * NN + j0];   // coalesced
            float bv1 = brow[(t0 + kk) * NN + j1];
            s0[kk] = fmaf(s0[kk], SCALE, bv0);
            s1[kk] = fmaf(s1[kk], SCALE, bv1);
        }

        // online softmax update, query 0
        float mt = s0[0];
        #pragma unroll
        for (int kk = 1; kk < 16; ++kk) mt = fmaxf(mt, s0[kk]);
        float mnew  = fmaxf(m0, mt);
        float alpha = __expf(m0 - mnew);
        float sl = 0.f;
        #pragma unroll
        for (int kk = 0; kk < 16; ++kk) { s0[kk] = __expf(s0[kk] - mnew); sl += s0[kk]; }
        l0 = l0 * alpha + sl; m0 = mnew;
        #pragma unroll
        for (int cc = 0; cc < 32; ++cc) o0[cc] *= alpha;

        // query 1
        mt = s1[0];
        #pragma unroll
        for (int kk = 1; kk < 16; ++kk) mt = fmaxf(mt, s1[kk]);
        mnew  = fmaxf(m1, mt);
        alpha = __expf(m1 - mnew);
        sl = 0.f;
        #pragma unroll
        for (int kk = 0; kk < 16; ++kk) { s1[kk] = __expf(s1[kk] - mnew); sl += s1[kk]; }
        l1 = l1 * alpha + sl; m1 = mnew;
        #pragma unroll
        for (int cc = 0; cc < 32; ++cc) o1[cc] *= alpha;

        // PV
        #pragma unroll
        for (int kk = 0; kk < 16; ++kk) {
            float p0v = s0[kk], p1v = s1[kk];
            const float4* vr = (const float4*)(Vsh + (t0 + kk) * CH);
            #pragma unroll
            for (int c4 = 0; c4 < 8; ++c4) {
                float4 vv = vr[c4];   // broadcast, shared by both queries
                o0[c4 * 4 + 0] = fmaf(p0v, vv.x, o0[c4 * 4 + 0]);
                o0[c4 * 4 + 1] = fmaf(p0v, vv.y, o0[c4 * 4 + 1]);
                o0[c4 * 4 + 2] = fmaf(p0v, vv.z, o0[c4 * 4 + 2]);
                o0[c4 * 4 + 3] = fmaf(p0v, vv.w, o0[c4 * 4 + 3]);
                o1[c4 * 4 + 0] = fmaf(p1v, vv.x, o1[c4 * 4 + 0]);
                o1[c4 * 4 + 1] = fmaf(p1v, vv.y, o1[c4 * 4 + 1]);
                o1[c4 * 4 + 2] = fmaf(p1v, vv.z, o1[c4 * 4 + 2]);
                o1[c4 * 4 + 3] = fmaf(p1v, vv.w, o1[c4 * 4 + 3]);
            }
        }
    }

    // ---- gating + store ----
    {
        const float invl = 1.0f / l0;
        const size_t pix = (size_t)i * NN + j0;
        const float4* gp  = (const float4*)(g_ws + pix * HC + h * CH);
        float4*       gop = (float4*)(go_ws + pix * HC + h * CH);
        #pragma unroll
        for (int c4 = 0; c4 < 8; ++c4) {
            float4 g4 = gp[c4];
            float4 r;
            r.x = g4.x * o0[c4 * 4 + 0] * invl;
            r.y = g4.y * o0[c4 * 4 + 1] * invl;
            r.z = g4.z * o0[c4 * 4 + 2] * invl;
            r.w = g4.w * o0[c4 * 4 + 3] * invl;
            gop[c4] = r;
        }
    }
    {
        const float invl = 1.0f / l1;
        const size_t pix = (size_t)i * NN + j1;
        const float4* gp  = (const float4*)(g_ws + pix * HC + h * CH);
        float4*       gop = (float4*)(go_ws + pix * HC + h * CH);
        #pragma unroll
        for (int c4 = 0; c4 < 8; ++c4) {
            float4 g4 = gp[c4];
            float4 r;
            r.x = g4.x * o1[c4 * 4 + 0] * invl;
            r.y = g4.y * o1[c4 * 4 + 1] * invl;
            r.z = g4.z * o1[c4 * 4 + 2] * invl;
            r.w = g4.w * o1[c4 * 4 + 3] * invl;
            gop[c4] = r;
        }
    }
}

// ---------------------------------------------------------------------------
// Kernel 3: out = go @ Wo   ([65536,128] @ [128,128])
// Thread tile: 4 pixels x 4 cols, b128 LDS broadcasts.
// ---------------------------------------------------------------------------
__global__ __launch_bounds__(256) void outproj_kernel(
    const float* __restrict__ go_ws, const float* __restrict__ Wo, float* __restrict__ out)
{
    __shared__ float gsh[32][132];
    const int t  = threadIdx.x;
    const int p0 = blockIdx.x * 32;

    const float4* g4 = (const float4*)(go_ws + (size_t)p0 * HC);
    #pragma unroll
    for (int r = 0; r < 4; ++r) {
        int idx4 = t + 256 * r;
        int p = idx4 >> 5, pos = idx4 & 31;
        *(float4*)&gsh[p][pos * 4] = g4[idx4];
    }
    __syncthreads();

    const int cg  = t & 31;           // 32 col groups x 4 cols
    const int pgr = t >> 5;           // 8 pixel groups x 4 pixels
    const int c0  = cg * 4;
    const int pp0 = pgr * 4;

    float4 acc[4];
    #pragma unroll
    for (int p = 0; p < 4; ++p) acc[p] = make_float4(0.f, 0.f, 0.f, 0.f);

    for (int d0 = 0; d0 < 128; d0 += 4) {
        float4 w0 = *(const float4*)(Wo + (size_t)(d0 + 0) * 128 + c0);
        float4 w1 = *(const float4*)(Wo + (size_t)(d0 + 1) * 128 + c0);
        float4 w2 = *(const float4*)(Wo + (size_t)(d0 + 2) * 128 + c0);
        float4 w3 = *(const float4*)(Wo + (size_t)(d0 + 3) * 128 + c0);
        #pragma unroll
        for (int p = 0; p < 4; ++p) {
            float4 zv = *(const float4*)&gsh[pp0 + p][d0];
            acc[p].x = fmaf(zv.x, w0.x, acc[p].x);
            acc[p].x = fmaf(zv.y, w1.x, acc[p].x);
            acc[p].x = fmaf(zv.z, w2.x, acc[p].x);
            acc[p].x = fmaf(zv.w, w3.x, acc[p].x);
            acc[p].y = fmaf(zv.x, w0.y, acc[p].y);
            acc[p].y = fmaf(zv.y, w1.y, acc[p].y);
            acc[p].y = fmaf(zv.z, w2.y, acc[p].y);
            acc[p].y = fmaf(zv.w, w3.y, acc[p].y);
            acc[p].z = fmaf(zv.x, w0.z, acc[p].z);
            acc[p].z = fmaf(zv.y, w1.z, acc[p].z);
            acc[p].z = fmaf(zv.z, w2.z, acc[p].z);
            acc[p].z = fmaf(zv.w, w3.z, acc[p].z);
            acc[p].w = fmaf(zv.x, w0.w, acc[p].w);
            acc[p].w = fmaf(zv.y, w1.w, acc[p].w);
            acc[p].w = fmaf(zv.z, w2.w, acc[p].w);
            acc[p].w = fmaf(zv.w, w3.w, acc[p].w);
        }
    }

    #pragma unroll
    for (int p = 0; p < 4; ++p)
        *(float4*)(out + (size_t)(p0 + pp0 + p) * HC + c0) = acc[p];
}

// ---------------------------------------------------------------------------
extern "C" void kernel_launch(void* const* d_in, const int* in_sizes, int n_in,
                              void* d_out, int out_size, void* d_ws, size_t ws_size,
                              hipStream_t stream)
{
    const float* z  = (const float*)d_in[0];
    const float* ls = (const float*)d_in[1];
    const float* lb = (const float*)d_in[2];
    const float* Wq = (const float*)d_in[3];
    const float* Wk = (const float*)d_in[4];
    const float* Wv = (const float*)d_in[5];
    const float* Wb = (const float*)d_in[6];
    const float* Wg = (const float*)d_in[7];
    const float* Wo = (const float*)d_in[8];

    float* ws = (float*)d_ws;
    const size_t BIG = (size_t)NPIX * HC;
    float* q_t    = ws;
    float* k_ws   = ws + BIG;
    float* v_ws   = ws + 2 * BIG;
    float* g_ws   = ws + 3 * BIG;
    float* go_ws  = ws + 4 * BIG;
    float* bias_t = ws + 5 * BIG;

    ln_proj_kernel<<<NPIX / 32, 256, 0, stream>>>(z, ls, lb, Wq, Wk, Wv, Wb, Wg,
                                                  q_t, k_ws, v_ws, g_ws, bias_t);
    attn_kernel<<<NN * NH, 128, 0, stream>>>(q_t, k_ws, v_ws, g_ws, bias_t, go_ws);
    outproj_kernel<<<NPIX / 32, 256, 0, stream>>>(go_ws, Wo, (float*)d_out);
}